// Round 3
// baseline (276.724 us; speedup 1.0000x reference)
//
#include <hip/hip_runtime.h>
#include <math.h>
#include <stdint.h>

// Math reduction (EPS=1e-12 negligible for x ~ N(0,1)):
//   gain_j = logit x_j exactly; base = sum_j softplus(x_j);
//   pos = sum_{m=1, x>0} x ; best = max_{m=1} x
//   per_sample = base - (pos>0 ? pos : best);  answer = mean over rows.
//
// Round-9: RETRY of the round-8 global_load_lds probe (HBM->L2->LDS DMA,
// no per-lane VGPR writeback, no L1). Round-8 failed with "container failed
// twice" — ambiguous infra-vs-kernel; audit found no fault vector (DMA
// sources 16B-aligned & clamped in-bounds, LDS dest wave-uniform with
// lane*16B inside the 4KB wave slice, per-wave vmcnt drain, literal size=16).
// Retrying once with hardened casts; if it fails again the same way, the
// global_load_lds path is implicated and we revert to the nt-load kernel.
//
// Why this probe: read wall is structure-insensitive (2.65 TB/s regular loads
// across occupancy/ILP sweeps; reg-pipeline neutral; nt loads -> ~3.7 TB/s)
// while the chip WRITES at 6.9 TB/s. Suspect = CU-side vector read-return
// (L1/MSHR/VGPR-writeback), shared by regular+nt. global_load_lds is the one
// read path that bypasses it. Per-wave-private LDS (8KB/wave, 32KB/block ->
// 20 waves/CU): no barriers, no cross-wave hazards.
// Finalize: bit-identical 2-stage tree (absmax 0.0 preserved).

constexpr int B = 32768;
constexpr int C = 1000;
constexpr int C4 = C / 4;                 // 250 float4 per row
constexpr int THREADS = 256;
constexpr int WAVES_PER_BLOCK = THREADS / 64;            // 4
constexpr int NBLOCKS = 2048;
constexpr int TOTAL_WAVES = NBLOCKS * WAVES_PER_BLOCK;   // 8192
constexpr int ROWS_PER_WAVE = B / TOTAL_WAVES;           // 4

typedef float f32x4 __attribute__((ext_vector_type(4)));
typedef __attribute__((address_space(3))) void lds_void_t;
typedef const __attribute__((address_space(1))) void gbl_void_t;

__device__ __forceinline__ void elem_update(float x, float m,
                                            float& base, float& pos, float& best) {
    // softplus(x) = max(x,0) + log(1 + exp(-|x|))
    float e  = __expf(-fabsf(x));
    float xp = fmaxf(x, 0.0f);
    base += xp + __logf(1.0f + e);
    pos  += m * xp;                       // m in {0,1}; only x>0 contributes
    if (m != 0.0f) best = fmaxf(best, x);
}

// HBM -> LDS direct (16B/lane). gsrc is PER-LANE; ldst must be wave-uniform:
// HW writes ldst + lane*16 (linear, m104).
__device__ __forceinline__ void gld_lds16(const void* gsrc, void* ldst) {
    __builtin_amdgcn_global_load_lds((gbl_void_t*)gsrc, (lds_void_t*)ldst,
                                     16, 0, 0);
}

__global__ __launch_bounds__(THREADS)
void row_loss_kernel(const float* __restrict__ X,
                     const float* __restrict__ M,
                     float* __restrict__ partial) {
    // per-wave private staging: 1024 floats X + 1024 floats M per wave
    __shared__ __align__(16) float ldsX[WAVES_PER_BLOCK][1024];
    __shared__ __align__(16) float ldsM[WAVES_PER_BLOCK][1024];

    const int w    = threadIdx.x >> 6;
    const int lane = threadIdx.x & 63;
    const int wid  = blockIdx.x * WAVES_PER_BLOCK + w;

    for (int k = 0; k < ROWS_PER_WAVE; ++k) {
        const int r = wid + k * TOTAL_WAVES;           // covers all rows once
        const f32x4* x4 = reinterpret_cast<const f32x4*>(X + (size_t)r * C);
        const f32x4* m4 = reinterpret_cast<const f32x4*>(M + (size_t)r * C);

        // Issue 8 DMA loads (4 X + 4 M), each wave-instr = 1024B to LDS.
        // Chunk 3 is ragged (idx 192..249): clamp per-lane SOURCE in-bounds
        // (rows are exactly 4000B); lanes 58..63 duplicate x4[249] into LDS
        // slots (float idx 1000..1023) that the consumer never reads.
        #pragma unroll
        for (int j = 0; j < 4; ++j) {
            const int idx = min(j * 64 + lane, C4 - 1);
            gld_lds16((const void*)(x4 + idx), (void*)&ldsX[w][j * 256]);
            gld_lds16((const void*)(m4 + idx), (void*)&ldsM[w][j * 256]);
        }
        // Drain this wave's DMA queue (vmcnt is per-wave; LDS region is
        // wave-private so no barrier). sched_barrier fences the ds_reads
        // below from being hoisted above the waitcnt (rule #18).
        asm volatile("s_waitcnt vmcnt(0)" ::: "memory");
        __builtin_amdgcn_sched_barrier(0);

        float base = 0.f, pos = 0.f, best = -INFINITY;
        #pragma unroll
        for (int j = 0; j < 4; ++j) {
            const int idx = j * 64 + lane;
            if (idx < C4) {
                f32x4 x = *reinterpret_cast<const f32x4*>(&ldsX[w][j * 256 + lane * 4]);
                f32x4 m = *reinterpret_cast<const f32x4*>(&ldsM[w][j * 256 + lane * 4]);
                elem_update(x.x, m.x, base, pos, best);
                elem_update(x.y, m.y, base, pos, best);
                elem_update(x.z, m.z, base, pos, best);
                elem_update(x.w, m.w, base, pos, best);
            }
        }
        // wave-level reduction (64 lanes), identical tree to prior rounds
        #pragma unroll
        for (int off = 32; off > 0; off >>= 1) {
            base += __shfl_down(base, off, 64);
            pos  += __shfl_down(pos,  off, 64);
            best  = fmaxf(best, __shfl_down(best, off, 64));
        }
        if (lane == 0) partial[r] = base - ((pos > 0.f) ? pos : best);
    }
}

// Stage 1: 64 blocks x 256 threads; block b reduces partial[512b .. 512b+511]
__global__ __launch_bounds__(256)
void finalize1_kernel(const float* __restrict__ partial, float* __restrict__ mid) {
    const int b = blockIdx.x;
    const int t = threadIdx.x;
    float v = partial[b * 512 + t] + partial[b * 512 + t + 256];

    #pragma unroll
    for (int off = 32; off > 0; off >>= 1)
        v += __shfl_down(v, off, 64);

    __shared__ float s[4];
    const int w    = t >> 6;
    const int lane = t & 63;
    if (lane == 0) s[w] = v;
    __syncthreads();
    if (t == 0) mid[b] = (s[0] + s[1]) + (s[2] + s[3]);
}

// Stage 2: 1 block x 64 threads; double-precision sum of 64 values, mean.
__global__ __launch_bounds__(64)
void finalize2_kernel(const float* __restrict__ mid, float* __restrict__ out) {
    double v = (double)mid[threadIdx.x];
    #pragma unroll
    for (int off = 32; off > 0; off >>= 1)
        v += __shfl_down(v, off, 64);
    if (threadIdx.x == 0) out[0] = (float)(v / (double)B);
}

extern "C" void kernel_launch(void* const* d_in, const int* in_sizes, int n_in,
                              void* d_out, int out_size, void* d_ws, size_t ws_size,
                              hipStream_t stream) {
    const float* X  = (const float*)d_in[0];
    const float* M  = (const float*)d_in[1];
    float* out      = (float*)d_out;
    float* partial  = (float*)d_ws;          // 32768 floats
    float* mid      = partial + B;           // 64 floats

    row_loss_kernel<<<NBLOCKS, THREADS, 0, stream>>>(X, M, partial);
    finalize1_kernel<<<64, 256, 0, stream>>>(partial, mid);
    finalize2_kernel<<<1, 64, 0, stream>>>(mid, out);
}

// Round 4
// 269.872 us; speedup vs baseline: 1.0254x; 1.0254x over previous
//
#include <hip/hip_runtime.h>
#include <math.h>
#include <stdint.h>

// Math reduction (EPS=1e-12 negligible for x ~ N(0,1)):
//   gain_j = logit x_j exactly; base = sum_j softplus(x_j);
//   pos = sum_{m=1, x>0} x ; best = max_{m=1} x
//   per_sample = base - (pos>0 ? pos : best);  answer = mean over rows.
//
// Round-10: DUAL-PATH probe. Evidence so far: three read paths pin at
// ~2.5-2.9 TB/s chip-wide (regular 2.65 / nt ~2.9 / LDS-DMA 2.5 serialized)
// while fills WRITE at 6.9 TB/s, and round-3 showed FETCH=131MB = half the
// read traffic (L2/L3 serves the rest) -> HBM BW is NOT the wall. Question:
// is the cap per-read-path (CU return machinery) or shared-downstream (XCD
// fabric/L3 read)? Test: run both paths CONCURRENTLY, each moving half the
// rows. Waves 0-1/block: pipelined nt register loads. Waves 2-3/block:
// pipelined LDS-DMA (2-row double-buffer, counted vmcnt(8) - fixes round-3's
// serialize-per-row confound). Independent walls -> ~2x (row ~50us);
// shared wall -> unchanged (~90us) and the read fabric is the roofline.
// Finalize: bit-identical 2-stage tree (absmax 0.0 preserved).

constexpr int B = 32768;
constexpr int C = 1000;
constexpr int C4 = C / 4;                 // 250 float4 per row
constexpr int THREADS = 256;
constexpr int WAVES_PER_BLOCK = 4;
constexpr int NBLOCKS = 2048;
constexpr int TOTAL_WAVES = NBLOCKS * WAVES_PER_BLOCK;   // 8192
constexpr int ROWS_PER_WAVE = B / TOTAL_WAVES;           // 4
constexpr int DMA_WAVES = 2;                             // waves 2,3

typedef float f32x4 __attribute__((ext_vector_type(4)));
typedef __attribute__((address_space(3))) void lds_void_t;
typedef const __attribute__((address_space(1))) void gbl_void_t;

__device__ __forceinline__ void elem_update(float x, float m,
                                            float& base, float& pos, float& best) {
    // softplus(x) = max(x,0) + log(1 + exp(-|x|))
    float e  = __expf(-fabsf(x));
    float xp = fmaxf(x, 0.0f);
    base += xp + __logf(1.0f + e);
    pos  += m * xp;                       // m in {0,1}; only x>0 contributes
    if (m != 0.0f) best = fmaxf(best, x);
}

__device__ __forceinline__ float finish_row(float base, float pos, float best) {
    #pragma unroll
    for (int off = 32; off > 0; off >>= 1) {
        base += __shfl_down(base, off, 64);
        pos  += __shfl_down(pos,  off, 64);
        best  = fmaxf(best, __shfl_down(best, off, 64));
    }
    return base - ((pos > 0.f) ? pos : best);
}

// ---------------- nt register path (waves 0-1) ----------------

__device__ __forceinline__ void load_row_nt(const float* __restrict__ Xrow,
                                            const float* __restrict__ Mrow,
                                            int lane,
                                            f32x4 (&xb)[4], f32x4 (&mb)[4]) {
    const f32x4* x4 = reinterpret_cast<const f32x4*>(Xrow);
    const f32x4* m4 = reinterpret_cast<const f32x4*>(Mrow);
    #pragma unroll
    for (int j = 0; j < 4; ++j) {
        const int idx = j * 64 + lane;
        if (idx < C4) {
            xb[j] = __builtin_nontemporal_load(x4 + idx);
            mb[j] = __builtin_nontemporal_load(m4 + idx);
        }
    }
}

__device__ __forceinline__ float row_result_reg(int lane,
                                                const f32x4 (&xb)[4],
                                                const f32x4 (&mb)[4]) {
    float base = 0.f, pos = 0.f, best = -INFINITY;
    #pragma unroll
    for (int j = 0; j < 4; ++j) {
        const int idx = j * 64 + lane;
        if (idx < C4) {
            elem_update(xb[j].x, mb[j].x, base, pos, best);
            elem_update(xb[j].y, mb[j].y, base, pos, best);
            elem_update(xb[j].z, mb[j].z, base, pos, best);
            elem_update(xb[j].w, mb[j].w, base, pos, best);
        }
    }
    return finish_row(base, pos, best);
}

// ---------------- LDS-DMA path (waves 2-3) ----------------

// HBM -> LDS direct (16B/lane). gsrc per-lane; ldst wave-uniform, HW writes
// ldst + lane*16 (linear, m104).
__device__ __forceinline__ void gld_lds16(const void* gsrc, void* ldst) {
    __builtin_amdgcn_global_load_lds((gbl_void_t*)gsrc, (lds_void_t*)ldst,
                                     16, 0, 0);
}

// Issue 8 DMA instrs (4 X + 4 M) for one row into one LDS buffer.
// Ragged chunk 3 (idx 192..249): clamp per-lane SOURCE in-bounds; lanes
// 58..63 duplicate x4[249] into LDS slots the consumer never reads.
__device__ __forceinline__ void issue_row_dma(const float* __restrict__ Xrow,
                                              const float* __restrict__ Mrow,
                                              int lane,
                                              float* ldsx, float* ldsm) {
    const f32x4* x4 = reinterpret_cast<const f32x4*>(Xrow);
    const f32x4* m4 = reinterpret_cast<const f32x4*>(Mrow);
    #pragma unroll
    for (int j = 0; j < 4; ++j) {
        const int idx = min(j * 64 + lane, C4 - 1);
        gld_lds16((const void*)(x4 + idx), (void*)(ldsx + j * 256));
        gld_lds16((const void*)(m4 + idx), (void*)(ldsm + j * 256));
    }
}

__device__ __forceinline__ float row_result_lds(int lane,
                                                const float* ldsx,
                                                const float* ldsm) {
    float base = 0.f, pos = 0.f, best = -INFINITY;
    #pragma unroll
    for (int j = 0; j < 4; ++j) {
        const int idx = j * 64 + lane;
        if (idx < C4) {
            f32x4 x = *reinterpret_cast<const f32x4*>(ldsx + j * 256 + lane * 4);
            f32x4 m = *reinterpret_cast<const f32x4*>(ldsm + j * 256 + lane * 4);
            elem_update(x.x, m.x, base, pos, best);
            elem_update(x.y, m.y, base, pos, best);
            elem_update(x.z, m.z, base, pos, best);
            elem_update(x.w, m.w, base, pos, best);
        }
    }
    return finish_row(base, pos, best);
}

__global__ __launch_bounds__(THREADS)
void row_loss_kernel(const float* __restrict__ X,
                     const float* __restrict__ M,
                     float* __restrict__ partial) {
    // staging only for the 2 DMA waves: 2 waves x 2 bufs x (4KB X + 4KB M)
    // = 32 KB/block -> 5 blocks/CU, 20 waves/CU.
    __shared__ __align__(16) float ldsX[DMA_WAVES][2][1024];
    __shared__ __align__(16) float ldsM[DMA_WAVES][2][1024];

    const int w    = threadIdx.x >> 6;
    const int lane = threadIdx.x & 63;
    const int wid  = blockIdx.x * WAVES_PER_BLOCK + w;
    const int row0 = wid * ROWS_PER_WAVE;            // contiguous 4-row span

    if (w < 2) {
        // ---- nt register path, 2-row software pipeline ----
        f32x4 xa[4], ma[4], xc[4], mc[4];
        load_row_nt(X + (size_t)row0 * C, M + (size_t)row0 * C, lane, xa, ma);
        #pragma unroll
        for (int k = 0; k < ROWS_PER_WAVE; ++k) {
            const int r = row0 + k;
            if (k + 1 < ROWS_PER_WAVE) {
                const float* Xn = X + (size_t)(r + 1) * C;
                const float* Mn = M + (size_t)(r + 1) * C;
                if (k & 1) load_row_nt(Xn, Mn, lane, xa, ma);
                else       load_row_nt(Xn, Mn, lane, xc, mc);
            }
            const float res = (k & 1) ? row_result_reg(lane, xc, mc)
                                      : row_result_reg(lane, xa, ma);
            if (lane == 0) partial[r] = res;
        }
    } else {
        // ---- LDS-DMA path, 2-row double buffer, counted vmcnt ----
        const int dw = w - 2;
        issue_row_dma(X + (size_t)row0 * C, M + (size_t)row0 * C, lane,
                      &ldsX[dw][0][0], &ldsM[dw][0][0]);
        #pragma unroll
        for (int k = 0; k < ROWS_PER_WAVE; ++k) {
            const int r   = row0 + k;
            const int cur = k & 1;
            if (k + 1 < ROWS_PER_WAVE) {
                issue_row_dma(X + (size_t)(r + 1) * C, M + (size_t)(r + 1) * C,
                              lane, &ldsX[dw][cur ^ 1][0], &ldsM[dw][cur ^ 1][0]);
                // wait for the OLDEST 8 (row k's DMAs); row k+1's 8 stay in
                // flight across the compute below (T4 counted-vmcnt).
                asm volatile("s_waitcnt vmcnt(8)" ::: "memory");
            } else {
                asm volatile("s_waitcnt vmcnt(0)" ::: "memory");
            }
            __builtin_amdgcn_sched_barrier(0);   // rule #18: pin ds_reads after wait
            const float res = row_result_lds(lane, &ldsX[dw][cur][0],
                                             &ldsM[dw][cur][0]);
            if (lane == 0) partial[r] = res;
        }
    }
}

// Stage 1: 64 blocks x 256 threads; block b reduces partial[512b .. 512b+511]
__global__ __launch_bounds__(256)
void finalize1_kernel(const float* __restrict__ partial, float* __restrict__ mid) {
    const int b = blockIdx.x;
    const int t = threadIdx.x;
    float v = partial[b * 512 + t] + partial[b * 512 + t + 256];

    #pragma unroll
    for (int off = 32; off > 0; off >>= 1)
        v += __shfl_down(v, off, 64);

    __shared__ float s[4];
    const int w    = t >> 6;
    const int lane = t & 63;
    if (lane == 0) s[w] = v;
    __syncthreads();
    if (t == 0) mid[b] = (s[0] + s[1]) + (s[2] + s[3]);
}

// Stage 2: 1 block x 64 threads; double-precision sum of 64 values, mean.
__global__ __launch_bounds__(64)
void finalize2_kernel(const float* __restrict__ mid, float* __restrict__ out) {
    double v = (double)mid[threadIdx.x];
    #pragma unroll
    for (int off = 32; off > 0; off >>= 1)
        v += __shfl_down(v, off, 64);
    if (threadIdx.x == 0) out[0] = (float)(v / (double)B);
}

extern "C" void kernel_launch(void* const* d_in, const int* in_sizes, int n_in,
                              void* d_out, int out_size, void* d_ws, size_t ws_size,
                              hipStream_t stream) {
    const float* X  = (const float*)d_in[0];
    const float* M  = (const float*)d_in[1];
    float* out      = (float*)d_out;
    float* partial  = (float*)d_ws;          // 32768 floats
    float* mid      = partial + B;           // 64 floats

    row_loss_kernel<<<NBLOCKS, THREADS, 0, stream>>>(X, M, partial);
    finalize1_kernel<<<64, 256, 0, stream>>>(partial, mid);
    finalize2_kernel<<<1, 64, 0, stream>>>(mid, out);
}

// Round 5
// 245.789 us; speedup vs baseline: 1.1259x; 1.0980x over previous
//
#include <hip/hip_runtime.h>
#include <math.h>

// Math reduction (EPS=1e-12 negligible for x ~ N(0,1)):
//   gain_j = logit x_j exactly; base = sum_j softplus(x_j);
//   pos = sum_{m=1, x>0} x ; best = max_{m=1} x
//   per_sample = base - (pos>0 ? pos : best);  answer = mean over rows.
//
// FINAL (round-11): revert to the round-0/round-6 structure — best measured
// dur_us 246.4. One 256-thread block per row, nt float4 loads, deterministic
// 2-stage finalize tree (absmax 0.0).
//
// Roofline case (why no further read-side optimization is attempted):
// streaming reads on this part cap at ~3.15 TB/s chip-wide regardless of
// mechanism or structure:
//   regular loads 2.65 | nt loads ~3.1 | LDS-DMA 2.5 | nt+DMA concurrent 3.16
//   (occupancy/ILP/MLP/pipelining all neutral across two sessions)
// Corroboration: m13's canonical float4 copy = 6.29 TB/s total = EXACTLY
// 3.145 read + 3.145 write; pure WRITE fills hit 6.9 TB/s; FETCH_SIZE shows
// HBM at ~20% -> the cap is the shared read-return fabric, upstream of path
// choice. Mandatory traffic = 262 MB (X+M, irreducible) / 3.15 TB/s = 83 us
// row-stage floor; this kernel measures 83-86 us. Remaining dur_us is the
// harness's ~152 us of poison fills + ~8 us finalize.

constexpr int B = 32768;
constexpr int C = 1000;
constexpr int C4 = C / 4;       // 250 float4 per row; threads 250..255 idle
constexpr int THREADS = 256;

typedef float f32x4 __attribute__((ext_vector_type(4)));

__device__ __forceinline__ void elem_update(float x, float m,
                                            float& base, float& pos, float& best) {
    // softplus(x) = max(x,0) + log(1 + exp(-|x|))
    float e  = __expf(-fabsf(x));
    float xp = fmaxf(x, 0.0f);
    base += xp + __logf(1.0f + e);
    pos  += m * xp;                       // m in {0,1}; only x>0 contributes
    if (m != 0.0f) best = fmaxf(best, x);
}

__global__ __launch_bounds__(THREADS)
void row_loss_kernel(const float* __restrict__ X,
                     const float* __restrict__ M,
                     float* __restrict__ partial) {
    const int row = blockIdx.x;
    const int t   = threadIdx.x;

    float base = 0.f, pos = 0.f, best = -INFINITY;

    if (t < C4) {
        const f32x4* x4 = reinterpret_cast<const f32x4*>(X + (size_t)row * C);
        const f32x4* m4 = reinterpret_cast<const f32x4*>(M + (size_t)row * C);
        f32x4 x = __builtin_nontemporal_load(x4 + t);   // nt: bypass L1 allocate
        f32x4 m = __builtin_nontemporal_load(m4 + t);
        elem_update(x.x, m.x, base, pos, best);
        elem_update(x.y, m.y, base, pos, best);
        elem_update(x.z, m.z, base, pos, best);
        elem_update(x.w, m.w, base, pos, best);
    }

    // wave-level reduction (64 lanes)
    #pragma unroll
    for (int off = 32; off > 0; off >>= 1) {
        base += __shfl_down(base, off, 64);
        pos  += __shfl_down(pos,  off, 64);
        best  = fmaxf(best, __shfl_down(best, off, 64));
    }

    __shared__ float sb[4], sp[4], ss[4];
    const int w    = t >> 6;
    const int lane = t & 63;
    if (lane == 0) { sb[w] = base; sp[w] = pos; ss[w] = best; }
    __syncthreads();
    if (t == 0) {
        float b = (sb[0] + sb[1]) + (sb[2] + sb[3]);
        float p = (sp[0] + sp[1]) + (sp[2] + sp[3]);
        float s = fmaxf(fmaxf(ss[0], ss[1]), fmaxf(ss[2], ss[3]));
        partial[row] = b - ((p > 0.f) ? p : s);
    }
}

// Stage 1: 64 blocks x 256 threads; block b reduces partial[512b .. 512b+511]
__global__ __launch_bounds__(256)
void finalize1_kernel(const float* __restrict__ partial, float* __restrict__ mid) {
    const int b = blockIdx.x;
    const int t = threadIdx.x;
    float v = partial[b * 512 + t] + partial[b * 512 + t + 256];

    #pragma unroll
    for (int off = 32; off > 0; off >>= 1)
        v += __shfl_down(v, off, 64);

    __shared__ float s[4];
    const int w    = t >> 6;
    const int lane = t & 63;
    if (lane == 0) s[w] = v;
    __syncthreads();
    if (t == 0) mid[b] = (s[0] + s[1]) + (s[2] + s[3]);
}

// Stage 2: 1 block x 64 threads; double-precision sum of 64 values, mean.
__global__ __launch_bounds__(64)
void finalize2_kernel(const float* __restrict__ mid, float* __restrict__ out) {
    double v = (double)mid[threadIdx.x];
    #pragma unroll
    for (int off = 32; off > 0; off >>= 1)
        v += __shfl_down(v, off, 64);
    if (threadIdx.x == 0) out[0] = (float)(v / (double)B);
}

extern "C" void kernel_launch(void* const* d_in, const int* in_sizes, int n_in,
                              void* d_out, int out_size, void* d_ws, size_t ws_size,
                              hipStream_t stream) {
    const float* X  = (const float*)d_in[0];
    const float* M  = (const float*)d_in[1];
    float* out      = (float*)d_out;
    float* partial  = (float*)d_ws;          // 32768 floats
    float* mid      = partial + B;           // 64 floats

    row_loss_kernel<<<B, THREADS, 0, stream>>>(X, M, partial);
    finalize1_kernel<<<64, 256, 0, stream>>>(partial, mid);
    finalize2_kernel<<<1, 64, 0, stream>>>(mid, out);
}